// Round 5
// baseline (151341.504 us; speedup 1.0000x reference)
//
#include <hip/hip_runtime.h>

typedef unsigned int u32_t;
typedef unsigned int u32x4 __attribute__((ext_vector_type(4)));

#define S_LEN 2048
#define EDIM  1024
#define HDIM  1024
#define GDIM  4096   // 4*H

#define POISON 0xAAAAAAAAu

// workspace layout (bytes)
//   ix    : 0        .. 33554432   [S][4H] f32
//   hslot : 33554432 .. 41943040   [S][H]  u32 (poison-init by harness)
//   flag  : 41943040 .. 42008576   [8][2048] u32  (zeroed by ix_gemm)
//   elect : 42008576 .. 42009088   [8] u32, 64B-strided (zeroed by ix_gemm)
//   mbox  : 42009088 .. 42074624   [8][2][1024] u32 (no init needed; flag-gated)
#define WS_HSLOT 33554432u
#define WS_FLAG  41943040u
#define WS_ELECT 42008576u
#define WS_MBOX  42009088u
#define ZINIT_WORDS 16512   // (flag 65536B + elect 512B)/4

// ---------------------------------------------------------------------------
// Phase A: ix[t][r] = emb[tokens[t]] . W_ih[r] + b_ih[r] + b_hh[r]
// fp32 LDS-tiled GEMM, 64x64 tile, BK=16, 256 threads, 4x4 micro-tile. ~92us.
// (unchanged except: block (0,0) also zeroes the flag+elect arrays, which
// the stream-ordered lstm_rec then consumes)
// ---------------------------------------------------------------------------
__global__ __launch_bounds__(256)
void ix_gemm(const int* __restrict__ tokens, const float* __restrict__ emb,
             const float* __restrict__ Wih, const float* __restrict__ bih,
             const float* __restrict__ bhh, float* __restrict__ ix,
             u32_t* __restrict__ zinit)
{
    __shared__ float As[16][68];
    __shared__ float Bs[16][68];
    const int t0  = blockIdx.x * 64;
    const int r0  = blockIdx.y * 64;
    const int tid = threadIdx.x;

    if (blockIdx.x == 0 && blockIdx.y == 0) {
        for (int i = tid; i < ZINIT_WORDS; i += 256) zinit[i] = 0u;
    }

    const int tx  = tid & 15;          // n-direction
    const int ty  = tid >> 4;          // m-direction
    const int m_a = tid & 63;          // staging row
    const int k_a = (tid >> 6) << 2;   // staging k offset: 0,4,8,12

    const float* arow = emb + (size_t)tokens[t0 + m_a] * EDIM + k_a;
    const float* brow = Wih + (size_t)(r0 + m_a) * EDIM + k_a;

    float acc[4][4] = {};
    for (int kk = 0; kk < EDIM; kk += 16) {
        float4 av = *(const float4*)(arow + kk);
        float4 bv = *(const float4*)(brow + kk);
        __syncthreads();
        As[k_a + 0][m_a] = av.x; As[k_a + 1][m_a] = av.y;
        As[k_a + 2][m_a] = av.z; As[k_a + 3][m_a] = av.w;
        Bs[k_a + 0][m_a] = bv.x; Bs[k_a + 1][m_a] = bv.y;
        Bs[k_a + 2][m_a] = bv.z; Bs[k_a + 3][m_a] = bv.w;
        __syncthreads();
#pragma unroll
        for (int k = 0; k < 16; ++k) {
            float4 a = *(const float4*)&As[k][ty << 2];
            float4 b = *(const float4*)&Bs[k][tx << 2];
            acc[0][0] += a.x * b.x; acc[0][1] += a.x * b.y;
            acc[0][2] += a.x * b.z; acc[0][3] += a.x * b.w;
            acc[1][0] += a.y * b.x; acc[1][1] += a.y * b.y;
            acc[1][2] += a.y * b.z; acc[1][3] += a.y * b.w;
            acc[2][0] += a.z * b.x; acc[2][1] += a.z * b.y;
            acc[2][2] += a.z * b.z; acc[2][3] += a.z * b.w;
            acc[3][0] += a.w * b.x; acc[3][1] += a.w * b.y;
            acc[3][2] += a.w * b.z; acc[3][3] += a.w * b.w;
        }
    }
    const int n0 = r0 + (tx << 2);
    float b0 = bih[n0 + 0] + bhh[n0 + 0];
    float b1 = bih[n0 + 1] + bhh[n0 + 1];
    float b2 = bih[n0 + 2] + bhh[n0 + 2];
    float b3 = bih[n0 + 3] + bhh[n0 + 3];
#pragma unroll
    for (int i = 0; i < 4; ++i) {
        int m = t0 + (ty << 2) + i;
        float4 v = make_float4(acc[i][0] + b0, acc[i][1] + b1,
                               acc[i][2] + b2, acc[i][3] + b3);
        *(float4*)(ix + (size_t)m * GDIM + n0) = v;
    }
}

// ---------------------------------------------------------------------------
// Phase B: persistent recurrence with per-XCD relay fan-out.
//
// Mechanism (R0-R3 evidence): dur tracked FETCH_SIZE at a constant ~44GB/s
// across ALL poll structures => the binding resource is per-LINE service
// serialization at the L3 coherence point (the polled row is only 64 lines;
// 256 blocks re-reading them bypass-scope = ~600 requests/line/step).
//
// Fix: ONE relay block per XCD (elected via HW_REG_XCC_ID + atomicAdd)
// keeps the exact baseline sticky L3 poll (8 pollers instead of 256).
// It forwards the row into a per-XCD mailbox with sc0 (L1-bypass, L2-LOCAL)
// stores and raises a per-(xcd,t) flag. The other 31 blocks/XCD poll only
// the flag via cheap sc0 L2 hits and then read the row from their own L2.
// Mailbox is parity-double-buffered; safe because the data dependency keeps
// all blocks within one step of each other (h[t+1] cannot exist anywhere
// until every block has consumed slot (t-1)&1). Flags are full-length and
// written once. Consumers have a bounded-spin fallback to the proven
// direct sticky poll (hang-proof even if election/flags misbehave).
// ---------------------------------------------------------------------------
__device__ __forceinline__ float fast_sigmoid(float x) {
    return 1.0f / (1.0f + __expf(-x));
}
__device__ __forceinline__ float fast_tanh(float x) {
    return 1.0f - 2.0f / (__expf(2.0f * x) + 1.0f);
}

#define ALOAD(p) __hip_atomic_load((p), __ATOMIC_RELAXED, __HIP_MEMORY_SCOPE_AGENT)

// sc0 = bypass L1, serve from the XCD-shared L2 (intra-XCD coherence point).
__device__ __forceinline__ u32_t l2load_u32(const u32_t* p) {
    u32_t v;
    asm volatile("global_load_dword %0, %1, off sc0\n\ts_waitcnt vmcnt(0)"
                 : "=v"(v) : "v"((unsigned long long)p) : "memory");
    return v;
}
__device__ __forceinline__ u32x4 l2load_u32x4(const u32_t* p) {
    u32x4 v;
    asm volatile("global_load_dwordx4 %0, %1, off sc0\n\ts_waitcnt vmcnt(0)"
                 : "=v"(v) : "v"((unsigned long long)p) : "memory");
    return v;
}
__device__ __forceinline__ void l2store_u32(u32_t* p, u32_t v) {
    asm volatile("global_store_dword %0, %1, off sc0"
                 :: "v"((unsigned long long)p), "v"(v) : "memory");
}
__device__ __forceinline__ void l2store_u32x4(u32_t* p, u32x4 v) {
    asm volatile("global_store_dwordx4 %0, %1, off sc0"
                 :: "v"((unsigned long long)p), "v"(v) : "memory");
}
__device__ __forceinline__ u32_t xcc_id() {
    u32_t x;
    asm("s_getreg_b32 %0, hwreg(HW_REG_XCC_ID)" : "=s"(x));
    return x & 7u;
}

__global__ __launch_bounds__(256)
void lstm_rec(const float* __restrict__ Whh,   // [4H, H]
              const float* __restrict__ ix,    // [S, 4H]
              u32_t* hslot,                    // [S][H] poison-init
              u32_t* flag,                     // [8][2048] zeroed
              u32_t* elect,                    // [8] 64B-strided, zeroed
              u32_t* mbox,                     // [8][2][1024]
              float* __restrict__ out)         // [H]
{
    const int tid  = threadIdx.x;
    const int wid  = tid >> 6;                 // 0..3
    const int lane = tid & 63;
    const int b    = blockIdx.x;
    const int j    = b * 4 + wid;              // 0..1023

    __shared__ float wlds[4][4][HDIM];         // 64 KB: [wave][gate][k]
    __shared__ float hs[2][HDIM];              // 8 KB, double-buffered
    __shared__ int sh_xcd, sh_relay, sh_fb;

    if (tid == 0) {
        u32_t x = xcc_id();
        sh_xcd = (int)x;
        u32_t old = atomicAdd(&elect[x * 16], 1u);   // device-scope (m20)
        sh_relay = (old == 0u) ? 1 : 0;
    }

    // Stage weights once: 16 rows x 4KB, float4-coalesced.
#pragma unroll
    for (int w = 0; w < 4; ++w)
#pragma unroll
        for (int g = 0; g < 4; ++g) {
            const float* row = Whh + (size_t)(g * HDIM + b * 4 + w) * HDIM;
            *(float4*)&wlds[w][g][tid << 2] = *(const float4*)(row + (tid << 2));
        }
    __syncthreads();                            // also publishes sh_xcd/sh_relay

    const int  xcd     = sh_xcd;
    const bool isRelay = (sh_relay != 0);
    u32_t* flagrow = flag + xcd * 2048;

    float c = 0.0f;
    u32_t p0 = POISON, p1 = POISON, p2 = POISON, p3 = POISON;

    for (int t = 0; t < S_LEN; ++t) {
        // ix contributions (wave-uniform); issued early, consumed post-reduce.
        const float* ixt = ix + (size_t)t * GDIM;
        float bi = ixt[j];
        float bf = ixt[HDIM + j];
        float bg = ixt[2 * HDIM + j];
        float bo = ixt[3 * HDIM + j];

        const int buf = t & 1;
        if (t == 0) {
            *(float4*)&hs[0][tid << 2] = make_float4(0.f, 0.f, 0.f, 0.f);
            __syncthreads();
        } else if (isRelay) {
            // --- relay: baseline sticky L3 poll (only 8 of these device-wide)
            const u32_t* src = hslot + (size_t)(t - 1) * HDIM + (tid << 2);
            for (;;) {
                bool m0 = (p0 == POISON), m1 = (p1 == POISON);
                bool m2 = (p2 == POISON), m3 = (p3 == POISON);
                if (!(m0 | m1 | m2 | m3)) break;
                if (m0) p0 = ALOAD(src + 0);
                if (m1) p1 = ALOAD(src + 1);
                if (m2) p2 = ALOAD(src + 2);
                if (m3) p3 = ALOAD(src + 3);
                __builtin_amdgcn_s_sleep(1);
            }
            // forward into XCD-local mailbox (L2), then publish flag
            u32_t* mr = mbox + ((xcd << 1) + ((t - 1) & 1)) * 1024;
            u32x4 v; v[0] = p0; v[1] = p1; v[2] = p2; v[3] = p3;
            l2store_u32x4(mr + (tid << 2), v);
            asm volatile("s_waitcnt vmcnt(0)" ::: "memory");  // data in L2
            *(float4*)&hs[buf][tid << 2] =
                make_float4(__uint_as_float(p0), __uint_as_float(p1),
                            __uint_as_float(p2), __uint_as_float(p3));
            __syncthreads();                     // all data stores complete
            if (tid == 0) l2store_u32(flagrow + (t - 1), 1u);
        } else {
            // --- consumer: poll L2-local flag, then read L2-local mailbox
            if (tid == 0) {
                int ok = 0;
                for (int it = 0; it < 1024; ++it) {
                    if (l2load_u32(flagrow + (t - 1)) == 1u) { ok = 1; break; }
                }
                sh_fb = ok;
            }
            __syncthreads();
            if (sh_fb) {
                const u32_t* mr = mbox + ((xcd << 1) + ((t - 1) & 1)) * 1024;
                u32x4 v = l2load_u32x4(mr + (tid << 2));
                *(float4*)&hs[buf][tid << 2] =
                    make_float4(__uint_as_float(v[0]), __uint_as_float(v[1]),
                                __uint_as_float(v[2]), __uint_as_float(v[3]));
            } else {
                // hang-proof fallback: proven direct sticky poll
                const u32_t* src = hslot + (size_t)(t - 1) * HDIM + (tid << 2);
                u32_t q0 = POISON, q1 = POISON, q2 = POISON, q3 = POISON;
                for (;;) {
                    bool m0 = (q0 == POISON), m1 = (q1 == POISON);
                    bool m2 = (q2 == POISON), m3 = (q3 == POISON);
                    if (!(m0 | m1 | m2 | m3)) break;
                    if (m0) q0 = ALOAD(src + 0);
                    if (m1) q1 = ALOAD(src + 1);
                    if (m2) q2 = ALOAD(src + 2);
                    if (m3) q3 = ALOAD(src + 3);
                    __builtin_amdgcn_s_sleep(1);
                }
                *(float4*)&hs[buf][tid << 2] =
                    make_float4(__uint_as_float(q0), __uint_as_float(q1),
                                __uint_as_float(q2), __uint_as_float(q3));
            }
            __syncthreads();
        }

        // 4 gates x 16 k-elements per lane; weights + h via ds_read_b128.
        float4 h0 = *(const float4*)&hs[buf][0 * 256 + (lane << 2)];
        float4 h1 = *(const float4*)&hs[buf][1 * 256 + (lane << 2)];
        float4 h2 = *(const float4*)&hs[buf][2 * 256 + (lane << 2)];
        float4 h3 = *(const float4*)&hs[buf][3 * 256 + (lane << 2)];

        float s[4];
#pragma unroll
        for (int g = 0; g < 4; ++g) {
            float4 w0 = *(const float4*)&wlds[wid][g][0 * 256 + (lane << 2)];
            float4 w1 = *(const float4*)&wlds[wid][g][1 * 256 + (lane << 2)];
            float4 w2 = *(const float4*)&wlds[wid][g][2 * 256 + (lane << 2)];
            float4 w3 = *(const float4*)&wlds[wid][g][3 * 256 + (lane << 2)];
            s[g] = w0.x*h0.x + w0.y*h0.y + w0.z*h0.z + w0.w*h0.w
                 + w1.x*h1.x + w1.y*h1.y + w1.z*h1.z + w1.w*h1.w
                 + w2.x*h2.x + w2.y*h2.y + w2.z*h2.z + w2.w*h2.w
                 + w3.x*h3.x + w3.y*h3.y + w3.z*h3.z + w3.w*h3.w;
        }

        // 64-lane butterfly all-reduce, 4 interleaved chains.
#pragma unroll
        for (int sh = 32; sh > 0; sh >>= 1) {
            s[0] += __shfl_xor(s[0], sh, 64);
            s[1] += __shfl_xor(s[1], sh, 64);
            s[2] += __shfl_xor(s[2], sh, 64);
            s[3] += __shfl_xor(s[3], sh, 64);
        }

        float si = s[0] + bi, sf = s[1] + bf, sg = s[2] + bg, so = s[3] + bo;
        float ig = fast_sigmoid(si);
        float fg = fast_sigmoid(sf);
        float og = fast_sigmoid(so);
        float gt = fast_tanh(sg);
        c = fg * c + ig * gt;                  // redundant across lanes (consistent)
        float h = og * fast_tanh(c);

        if (lane == 0) {
            u32_t hb = __float_as_uint(h);
            if (hb == POISON) hb = 0u;         // hang-proof canonicalization
            __hip_atomic_store(hslot + (size_t)t * HDIM + j, hb,
                               __ATOMIC_RELAXED, __HIP_MEMORY_SCOPE_AGENT);
            if (t == S_LEN - 1) out[j] = h;
        }

        // Relay-only: speculative async prefetch of next step's 4 dwords;
        // stragglers re-polled at the top of the next iteration. Consumers
        // issue NO hslot traffic at all -- that's the 32x requester cut.
        if (isRelay) {
            const u32_t* nsrc = hslot + (size_t)t * HDIM + (tid << 2);
            p0 = ALOAD(nsrc + 0);
            p1 = ALOAD(nsrc + 1);
            p2 = ALOAD(nsrc + 2);
            p3 = ALOAD(nsrc + 3);
        }
    }
}

// ---------------------------------------------------------------------------
extern "C" void kernel_launch(void* const* d_in, const int* in_sizes, int n_in,
                              void* d_out, int out_size, void* d_ws, size_t ws_size,
                              hipStream_t stream) {
    const int*   tokens = (const int*)  d_in[0];
    const float* emb    = (const float*)d_in[1];
    const float* Wih    = (const float*)d_in[2];
    const float* Whh    = (const float*)d_in[3];
    const float* bih    = (const float*)d_in[4];
    const float* bhh    = (const float*)d_in[5];
    float* out = (float*)d_out;

    float* ix    = (float*)d_ws;
    u32_t* hslot = (u32_t*)((char*)d_ws + WS_HSLOT);
    u32_t* flag  = (u32_t*)((char*)d_ws + WS_FLAG);
    u32_t* elect = (u32_t*)((char*)d_ws + WS_ELECT);
    u32_t* mbox  = (u32_t*)((char*)d_ws + WS_MBOX);
    // total ws use: ~42.1 MB

    dim3 gA(S_LEN / 64, GDIM / 64);
    hipLaunchKernelGGL(ix_gemm, gA, dim3(256), 0, stream,
                       tokens, emb, Wih, bih, bhh, ix, flag);
    hipLaunchKernelGGL(lstm_rec, dim3(256), dim3(256), 0, stream,
                       Whh, ix, hslot, flag, elect, mbox, out);
}

// Round 6
// 12584.595 us; speedup vs baseline: 12.0259x; 12.0259x over previous
//
#include <hip/hip_runtime.h>

typedef unsigned int u32_t;

#define S_LEN 2048
#define EDIM  1024
#define HDIM  1024
#define GDIM  4096   // 4*H

#define POISON 0xAAAAAAAAu

// Re-poll epoch: 32 realtime ticks (s_memrealtime ~100 MHz => ~320 ns ~ 770
// device cycles), matching the baseline's natural poll round trip. Power of
// 2 so the grid alignment is a mask.
#define EPOCH_TICKS 32ull

// ---------------------------------------------------------------------------
// Phase A: ix[t][r] = emb[tokens[t]] . W_ih[r] + b_ih[r] + b_hh[r]
// fp32 LDS-tiled GEMM, 64x64 tile, BK=16, 256 threads, 4x4 micro-tile. ~92us.
// (unchanged from the 5612us baseline)
// ---------------------------------------------------------------------------
__global__ __launch_bounds__(256)
void ix_gemm(const int* __restrict__ tokens, const float* __restrict__ emb,
             const float* __restrict__ Wih, const float* __restrict__ bih,
             const float* __restrict__ bhh, float* __restrict__ ix)
{
    __shared__ float As[16][68];
    __shared__ float Bs[16][68];
    const int t0  = blockIdx.x * 64;
    const int r0  = blockIdx.y * 64;
    const int tid = threadIdx.x;
    const int tx  = tid & 15;          // n-direction
    const int ty  = tid >> 4;          // m-direction
    const int m_a = tid & 63;          // staging row
    const int k_a = (tid >> 6) << 2;   // staging k offset: 0,4,8,12

    const float* arow = emb + (size_t)tokens[t0 + m_a] * EDIM + k_a;
    const float* brow = Wih + (size_t)(r0 + m_a) * EDIM + k_a;

    float acc[4][4] = {};
    for (int kk = 0; kk < EDIM; kk += 16) {
        float4 av = *(const float4*)(arow + kk);
        float4 bv = *(const float4*)(brow + kk);
        __syncthreads();
        As[k_a + 0][m_a] = av.x; As[k_a + 1][m_a] = av.y;
        As[k_a + 2][m_a] = av.z; As[k_a + 3][m_a] = av.w;
        Bs[k_a + 0][m_a] = bv.x; Bs[k_a + 1][m_a] = bv.y;
        Bs[k_a + 2][m_a] = bv.z; Bs[k_a + 3][m_a] = bv.w;
        __syncthreads();
#pragma unroll
        for (int k = 0; k < 16; ++k) {
            float4 a = *(const float4*)&As[k][ty << 2];
            float4 b = *(const float4*)&Bs[k][tx << 2];
            acc[0][0] += a.x * b.x; acc[0][1] += a.x * b.y;
            acc[0][2] += a.x * b.z; acc[0][3] += a.x * b.w;
            acc[1][0] += a.y * b.x; acc[1][1] += a.y * b.y;
            acc[1][2] += a.y * b.z; acc[1][3] += a.y * b.w;
            acc[2][0] += a.z * b.x; acc[2][1] += a.z * b.y;
            acc[2][2] += a.z * b.z; acc[2][3] += a.z * b.w;
            acc[3][0] += a.w * b.x; acc[3][1] += a.w * b.y;
            acc[3][2] += a.w * b.z; acc[3][3] += a.w * b.w;
        }
    }
    const int n0 = r0 + (tx << 2);
    float b0 = bih[n0 + 0] + bhh[n0 + 0];
    float b1 = bih[n0 + 1] + bhh[n0 + 1];
    float b2 = bih[n0 + 2] + bhh[n0 + 2];
    float b3 = bih[n0 + 3] + bhh[n0 + 3];
#pragma unroll
    for (int i = 0; i < 4; ++i) {
        int m = t0 + (ty << 2) + i;
        float4 v = make_float4(acc[i][0] + b0, acc[i][1] + b1,
                               acc[i][2] + b2, acc[i][3] + b3);
        *(float4*)(ix + (size_t)m * GDIM + n0) = v;
    }
}

// ---------------------------------------------------------------------------
// Phase B: persistent recurrence — EXACT 5612us baseline structure
// (4x4B sticky relaxed-agent atomic re-polls, ix loads at top, hs double-
// buffer, one barrier/step, async bottom prefetch).
//
// ONE change vs baseline: the re-poll throttle is no longer a free-running
// s_sleep(1) but a wait until the next ABSOLUTE s_memrealtime epoch
// boundary (EPOCH_TICKS grid, shared clock). Rationale: the per-step period
// is a max over 256 blocks; with independent poll phases the expected max
// is mean + ~3 sigma of the detect distribution. Synchronizing all blocks'
// re-polls onto one wall-clock grid makes the detect tick common-mode
// across blocks (the first tick after the last producer store is the SAME
// tick for everyone), collapsing the straggler amplification. Fast path
// (prefetch already complete) is untouched; the gate provably terminates.
// R4's sc0 mailbox is fully reverted (gfx950 sc0/sc1 are scope encodings;
// sc0-only polls serve from own L1 and never observe remote stores).
// ---------------------------------------------------------------------------
__device__ __forceinline__ float fast_sigmoid(float x) {
    return 1.0f / (1.0f + __expf(-x));
}
__device__ __forceinline__ float fast_tanh(float x) {
    return 1.0f - 2.0f / (__expf(2.0f * x) + 1.0f);
}

__global__ __launch_bounds__(256)
void lstm_rec(const float* __restrict__ Whh,   // [4H, H]
              const float* __restrict__ ix,    // [S, 4H]
              u32_t* hslot,                    // [S][H] poison-init
              float* __restrict__ out)         // [H]
{
    const int tid  = threadIdx.x;
    const int wid  = tid >> 6;                 // 0..3
    const int lane = tid & 63;
    const int b    = blockIdx.x;
    const int j    = b * 4 + wid;              // 0..1023

    __shared__ float wlds[4][4][HDIM];         // 64 KB: [wave][gate][k]
    __shared__ float hs[2][HDIM];              // 8 KB, double-buffered

    // Stage weights once: 16 rows x 4KB, float4-coalesced.
#pragma unroll
    for (int w = 0; w < 4; ++w)
#pragma unroll
        for (int g = 0; g < 4; ++g) {
            const float* row = Whh + (size_t)(g * HDIM + b * 4 + w) * HDIM;
            *(float4*)&wlds[w][g][tid << 2] = *(const float4*)(row + (tid << 2));
        }
    __syncthreads();

    float c = 0.0f;
    u32_t p0 = POISON, p1 = POISON, p2 = POISON, p3 = POISON;

    for (int t = 0; t < S_LEN; ++t) {
        // ix contributions (wave-uniform); issued early, consumed post-reduce.
        const float* ixt = ix + (size_t)t * GDIM;
        float bi = ixt[j];
        float bf = ixt[HDIM + j];
        float bg = ixt[2 * HDIM + j];
        float bo = ixt[3 * HDIM + j];

        const int buf = t & 1;
        if (t == 0) {
            *(float4*)&hs[0][tid << 2] = make_float4(0.f, 0.f, 0.f, 0.f);
        } else {
            const u32_t* src = hslot + (size_t)(t - 1) * HDIM + (tid << 2);
            for (;;) {
                bool m0 = (p0 == POISON), m1 = (p1 == POISON);
                bool m2 = (p2 == POISON), m3 = (p3 == POISON);
                if (!(m0 | m1 | m2 | m3)) break;
                // Synchronized volley: wait for the next absolute epoch
                // boundary on the shared realtime clock, so all blocks
                // re-poll at the same wall-clock ticks (common-mode detect).
                {
                    unsigned long long rt = __builtin_amdgcn_s_memrealtime();
                    unsigned long long tgt =
                        (rt & ~(EPOCH_TICKS - 1ull)) + EPOCH_TICKS;
                    do {
                        rt = __builtin_amdgcn_s_memrealtime();
                    } while (rt < tgt);
                }
                if (m0) p0 = __hip_atomic_load(src + 0, __ATOMIC_RELAXED, __HIP_MEMORY_SCOPE_AGENT);
                if (m1) p1 = __hip_atomic_load(src + 1, __ATOMIC_RELAXED, __HIP_MEMORY_SCOPE_AGENT);
                if (m2) p2 = __hip_atomic_load(src + 2, __ATOMIC_RELAXED, __HIP_MEMORY_SCOPE_AGENT);
                if (m3) p3 = __hip_atomic_load(src + 3, __ATOMIC_RELAXED, __HIP_MEMORY_SCOPE_AGENT);
            }
            *(float4*)&hs[buf][tid << 2] =
                make_float4(__uint_as_float(p0), __uint_as_float(p1),
                            __uint_as_float(p2), __uint_as_float(p3));
        }
        __syncthreads();   // single barrier/step (hs double-buffered)

        // 4 gates x 16 k-elements per lane; weights + h via ds_read_b128.
        float4 h0 = *(const float4*)&hs[buf][0 * 256 + (lane << 2)];
        float4 h1 = *(const float4*)&hs[buf][1 * 256 + (lane << 2)];
        float4 h2 = *(const float4*)&hs[buf][2 * 256 + (lane << 2)];
        float4 h3 = *(const float4*)&hs[buf][3 * 256 + (lane << 2)];

        float s[4];
#pragma unroll
        for (int g = 0; g < 4; ++g) {
            float4 w0 = *(const float4*)&wlds[wid][g][0 * 256 + (lane << 2)];
            float4 w1 = *(const float4*)&wlds[wid][g][1 * 256 + (lane << 2)];
            float4 w2 = *(const float4*)&wlds[wid][g][2 * 256 + (lane << 2)];
            float4 w3 = *(const float4*)&wlds[wid][g][3 * 256 + (lane << 2)];
            s[g] = w0.x*h0.x + w0.y*h0.y + w0.z*h0.z + w0.w*h0.w
                 + w1.x*h1.x + w1.y*h1.y + w1.z*h1.z + w1.w*h1.w
                 + w2.x*h2.x + w2.y*h2.y + w2.z*h2.z + w2.w*h2.w
                 + w3.x*h3.x + w3.y*h3.y + w3.z*h3.z + w3.w*h3.w;
        }

        // 64-lane butterfly all-reduce, 4 interleaved chains.
#pragma unroll
        for (int sh = 32; sh > 0; sh >>= 1) {
            s[0] += __shfl_xor(s[0], sh, 64);
            s[1] += __shfl_xor(s[1], sh, 64);
            s[2] += __shfl_xor(s[2], sh, 64);
            s[3] += __shfl_xor(s[3], sh, 64);
        }

        float si = s[0] + bi, sf = s[1] + bf, sg = s[2] + bg, so = s[3] + bo;
        float ig = fast_sigmoid(si);
        float fg = fast_sigmoid(sf);
        float og = fast_sigmoid(so);
        float gt = fast_tanh(sg);
        c = fg * c + ig * gt;                  // redundant across lanes (consistent)
        float h = og * fast_tanh(c);

        if (lane == 0) {
            u32_t hb = __float_as_uint(h);
            if (hb == POISON) hb = 0u;         // hang-proof canonicalization
            __hip_atomic_store(hslot + (size_t)t * HDIM + j, hb,
                               __ATOMIC_RELAXED, __HIP_MEMORY_SCOPE_AGENT);
            if (t == S_LEN - 1) out[j] = h;
        }

        // Speculative async prefetch of next step's 4 dwords; stragglers
        // re-polled (epoch-gated) at the top of the next iteration.
        const u32_t* nsrc = hslot + (size_t)t * HDIM + (tid << 2);
        p0 = __hip_atomic_load(nsrc + 0, __ATOMIC_RELAXED, __HIP_MEMORY_SCOPE_AGENT);
        p1 = __hip_atomic_load(nsrc + 1, __ATOMIC_RELAXED, __HIP_MEMORY_SCOPE_AGENT);
        p2 = __hip_atomic_load(nsrc + 2, __ATOMIC_RELAXED, __HIP_MEMORY_SCOPE_AGENT);
        p3 = __hip_atomic_load(nsrc + 3, __ATOMIC_RELAXED, __HIP_MEMORY_SCOPE_AGENT);
        // No trailing barrier: hs double-buffered; a wave is at most one
        // barrier ahead and writes only the other buffer.
    }
}

// ---------------------------------------------------------------------------
extern "C" void kernel_launch(void* const* d_in, const int* in_sizes, int n_in,
                              void* d_out, int out_size, void* d_ws, size_t ws_size,
                              hipStream_t stream) {
    const int*   tokens = (const int*)  d_in[0];
    const float* emb    = (const float*)d_in[1];
    const float* Wih    = (const float*)d_in[2];
    const float* Whh    = (const float*)d_in[3];
    const float* bih    = (const float*)d_in[4];
    const float* bhh    = (const float*)d_in[5];
    float* out = (float*)d_out;

    float* ix    = (float*)d_ws;                                     // 33.55 MB
    u32_t* hslot = (u32_t*)((char*)d_ws + (size_t)S_LEN * GDIM * 4); // 8 MB
    // total ws use: 41.9 MB

    dim3 gA(S_LEN / 64, GDIM / 64);
    hipLaunchKernelGGL(ix_gemm, gA, dim3(256), 0, stream,
                       tokens, emb, Wih, bih, bhh, ix);
    hipLaunchKernelGGL(lstm_rec, dim3(256), dim3(256), 0, stream,
                       Whh, ix, hslot, out);
}

// Round 7
// 10308.168 us; speedup vs baseline: 14.6817x; 1.2208x over previous
//
#include <hip/hip_runtime.h>

typedef unsigned int u32_t;

#define S_LEN 2048
#define EDIM  1024
#define HDIM  1024
#define GDIM  4096   // 4*H

#define POISON 0xAAAAAAAAu

// Phase-B grid shape: 128 blocks x 512 threads (8 waves). Halves the number
// of blocks polling the coherence point vs the 256x256 baseline, with the
// protocol otherwise IDENTICAL. LDS: 8 waves x 4 gates x 4KB weights =
// 128KB + 8KB hs = 136KB (< 160KB/CU).
#define NBLK 128
#define TPB  512
#define JPB  8     // j-rows per block = waves per block

// ---------------------------------------------------------------------------
// Phase A: ix[t][r] = emb[tokens[t]] . W_ih[r] + b_ih[r] + b_hh[r]
// fp32 LDS-tiled GEMM, 64x64 tile, BK=16, 256 threads, 4x4 micro-tile. ~92us.
// (unchanged from the 5612us baseline)
// ---------------------------------------------------------------------------
__global__ __launch_bounds__(256)
void ix_gemm(const int* __restrict__ tokens, const float* __restrict__ emb,
             const float* __restrict__ Wih, const float* __restrict__ bih,
             const float* __restrict__ bhh, float* __restrict__ ix)
{
    __shared__ float As[16][68];
    __shared__ float Bs[16][68];
    const int t0  = blockIdx.x * 64;
    const int r0  = blockIdx.y * 64;
    const int tid = threadIdx.x;
    const int tx  = tid & 15;          // n-direction
    const int ty  = tid >> 4;          // m-direction
    const int m_a = tid & 63;          // staging row
    const int k_a = (tid >> 6) << 2;   // staging k offset: 0,4,8,12

    const float* arow = emb + (size_t)tokens[t0 + m_a] * EDIM + k_a;
    const float* brow = Wih + (size_t)(r0 + m_a) * EDIM + k_a;

    float acc[4][4] = {};
    for (int kk = 0; kk < EDIM; kk += 16) {
        float4 av = *(const float4*)(arow + kk);
        float4 bv = *(const float4*)(brow + kk);
        __syncthreads();
        As[k_a + 0][m_a] = av.x; As[k_a + 1][m_a] = av.y;
        As[k_a + 2][m_a] = av.z; As[k_a + 3][m_a] = av.w;
        Bs[k_a + 0][m_a] = bv.x; Bs[k_a + 1][m_a] = bv.y;
        Bs[k_a + 2][m_a] = bv.z; Bs[k_a + 3][m_a] = bv.w;
        __syncthreads();
#pragma unroll
        for (int k = 0; k < 16; ++k) {
            float4 a = *(const float4*)&As[k][ty << 2];
            float4 b = *(const float4*)&Bs[k][tx << 2];
            acc[0][0] += a.x * b.x; acc[0][1] += a.x * b.y;
            acc[0][2] += a.x * b.z; acc[0][3] += a.x * b.w;
            acc[1][0] += a.y * b.x; acc[1][1] += a.y * b.y;
            acc[1][2] += a.y * b.z; acc[1][3] += a.y * b.w;
            acc[2][0] += a.z * b.x; acc[2][1] += a.z * b.y;
            acc[2][2] += a.z * b.z; acc[2][3] += a.z * b.w;
            acc[3][0] += a.w * b.x; acc[3][1] += a.w * b.y;
            acc[3][2] += a.w * b.z; acc[3][3] += a.w * b.w;
        }
    }
    const int n0 = r0 + (tx << 2);
    float b0 = bih[n0 + 0] + bhh[n0 + 0];
    float b1 = bih[n0 + 1] + bhh[n0 + 1];
    float b2 = bih[n0 + 2] + bhh[n0 + 2];
    float b3 = bih[n0 + 3] + bhh[n0 + 3];
#pragma unroll
    for (int i = 0; i < 4; ++i) {
        int m = t0 + (ty << 2) + i;
        float4 v = make_float4(acc[i][0] + b0, acc[i][1] + b1,
                               acc[i][2] + b2, acc[i][3] + b3);
        *(float4*)(ix + (size_t)m * GDIM + n0) = v;
    }
}

// ---------------------------------------------------------------------------
// Phase B: persistent recurrence. Protocol IDENTICAL to the proven 5612us
// baseline (4x sticky relaxed-agent atomic dword polls -> here 2x per
// thread, s_sleep(1) throttle, async bottom prefetch, ix loads at top,
// hs double-buffer, one barrier/step). ONE variable changed: grid shape
// 256x256 -> 128x512. This halves the number of blocks hammering each
// polled cache line at the coherence point (128 wave-requests/line/round
// instead of 256) -- the cleanest isolation of the congestion term that
// R0-R5 never managed to test without confounds. Per-lane compute and
// device-wide FLOPs are unchanged; 8 waves/block, wave w owns gate rows
// {j, H+j, 2H+j, 3H+j}, j = 8*block + w.
// ---------------------------------------------------------------------------
__device__ __forceinline__ float fast_sigmoid(float x) {
    return 1.0f / (1.0f + __expf(-x));
}
__device__ __forceinline__ float fast_tanh(float x) {
    return 1.0f - 2.0f / (__expf(2.0f * x) + 1.0f);
}

#define ALOAD(p) __hip_atomic_load((p), __ATOMIC_RELAXED, __HIP_MEMORY_SCOPE_AGENT)

__global__ __launch_bounds__(TPB)
void lstm_rec(const float* __restrict__ Whh,   // [4H, H]
              const float* __restrict__ ix,    // [S, 4H]
              u32_t* hslot,                    // [S][H] poison-init
              float* __restrict__ out)         // [H]
{
    const int tid  = threadIdx.x;
    const int wid  = tid >> 6;                 // 0..7
    const int lane = tid & 63;
    const int b    = blockIdx.x;
    const int j    = b * JPB + wid;            // 0..1023

    __shared__ float wlds[JPB][4][HDIM];       // 128 KB: [wave][gate][k]
    __shared__ float hs[2][HDIM];              // 8 KB, double-buffered

    // Stage weights once: 32 rows x 4KB, float2-coalesced (512 threads).
#pragma unroll
    for (int w = 0; w < JPB; ++w)
#pragma unroll
        for (int g = 0; g < 4; ++g) {
            const float* row = Whh + (size_t)(g * HDIM + b * JPB + w) * HDIM;
            *(float2*)&wlds[w][g][tid << 1] = *(const float2*)(row + (tid << 1));
        }
    __syncthreads();

    float c = 0.0f;
    u32_t p0 = POISON, p1 = POISON;            // 2 polled dwords per thread

    for (int t = 0; t < S_LEN; ++t) {
        // ix contributions (wave-uniform); issued early, consumed post-reduce.
        const float* ixt = ix + (size_t)t * GDIM;
        float bi = ixt[j];
        float bf = ixt[HDIM + j];
        float bg = ixt[2 * HDIM + j];
        float bo = ixt[3 * HDIM + j];

        const int buf = t & 1;
        if (t == 0) {
            *(float2*)&hs[0][tid << 1] = make_float2(0.f, 0.f);
        } else {
            const u32_t* src = hslot + (size_t)(t - 1) * HDIM + (tid << 1);
            for (;;) {
                bool m0 = (p0 == POISON), m1 = (p1 == POISON);
                if (!(m0 | m1)) break;
                if (m0) p0 = ALOAD(src + 0);
                if (m1) p1 = ALOAD(src + 1);
                __builtin_amdgcn_s_sleep(1);   // throttle fabric poll storm
            }
            *(float2*)&hs[buf][tid << 1] =
                make_float2(__uint_as_float(p0), __uint_as_float(p1));
        }
        __syncthreads();   // single barrier/step (hs double-buffered)

        // 4 gates x 16 k-elements per lane; weights + h via ds_read_b128.
        float4 h0 = *(const float4*)&hs[buf][0 * 256 + (lane << 2)];
        float4 h1 = *(const float4*)&hs[buf][1 * 256 + (lane << 2)];
        float4 h2 = *(const float4*)&hs[buf][2 * 256 + (lane << 2)];
        float4 h3 = *(const float4*)&hs[buf][3 * 256 + (lane << 2)];

        float s[4];
#pragma unroll
        for (int g = 0; g < 4; ++g) {
            float4 w0 = *(const float4*)&wlds[wid][g][0 * 256 + (lane << 2)];
            float4 w1 = *(const float4*)&wlds[wid][g][1 * 256 + (lane << 2)];
            float4 w2 = *(const float4*)&wlds[wid][g][2 * 256 + (lane << 2)];
            float4 w3 = *(const float4*)&wlds[wid][g][3 * 256 + (lane << 2)];
            s[g] = w0.x*h0.x + w0.y*h0.y + w0.z*h0.z + w0.w*h0.w
                 + w1.x*h1.x + w1.y*h1.y + w1.z*h1.z + w1.w*h1.w
                 + w2.x*h2.x + w2.y*h2.y + w2.z*h2.z + w2.w*h2.w
                 + w3.x*h3.x + w3.y*h3.y + w3.z*h3.z + w3.w*h3.w;
        }

        // 64-lane butterfly all-reduce, 4 interleaved chains.
#pragma unroll
        for (int sh = 32; sh > 0; sh >>= 1) {
            s[0] += __shfl_xor(s[0], sh, 64);
            s[1] += __shfl_xor(s[1], sh, 64);
            s[2] += __shfl_xor(s[2], sh, 64);
            s[3] += __shfl_xor(s[3], sh, 64);
        }

        float si = s[0] + bi, sf = s[1] + bf, sg = s[2] + bg, so = s[3] + bo;
        float ig = fast_sigmoid(si);
        float fg = fast_sigmoid(sf);
        float og = fast_sigmoid(so);
        float gt = fast_tanh(sg);
        c = fg * c + ig * gt;                  // redundant across lanes (consistent)
        float h = og * fast_tanh(c);

        if (lane == 0) {
            u32_t hb = __float_as_uint(h);
            if (hb == POISON) hb = 0u;         // hang-proof canonicalization
            __hip_atomic_store(hslot + (size_t)t * HDIM + j, hb,
                               __ATOMIC_RELAXED, __HIP_MEMORY_SCOPE_AGENT);
            if (t == S_LEN - 1) out[j] = h;
        }

        // Speculative async prefetch of next step's 2 dwords; stragglers
        // re-polled at the top of the next iteration.
        const u32_t* nsrc = hslot + (size_t)t * HDIM + (tid << 1);
        p0 = ALOAD(nsrc + 0);
        p1 = ALOAD(nsrc + 1);
        // No trailing barrier: hs double-buffered; a wave is at most one
        // barrier ahead and writes only the other buffer.
    }
}

// ---------------------------------------------------------------------------
extern "C" void kernel_launch(void* const* d_in, const int* in_sizes, int n_in,
                              void* d_out, int out_size, void* d_ws, size_t ws_size,
                              hipStream_t stream) {
    const int*   tokens = (const int*)  d_in[0];
    const float* emb    = (const float*)d_in[1];
    const float* Wih    = (const float*)d_in[2];
    const float* Whh    = (const float*)d_in[3];
    const float* bih    = (const float*)d_in[4];
    const float* bhh    = (const float*)d_in[5];
    float* out = (float*)d_out;

    float* ix    = (float*)d_ws;                                     // 33.55 MB
    u32_t* hslot = (u32_t*)((char*)d_ws + (size_t)S_LEN * GDIM * 4); // 8 MB
    // total ws use: 41.9 MB

    dim3 gA(S_LEN / 64, GDIM / 64);
    hipLaunchKernelGGL(ix_gemm, gA, dim3(256), 0, stream,
                       tokens, emb, Wih, bih, bhh, ix);
    hipLaunchKernelGGL(lstm_rec, dim3(NBLK), dim3(TPB), 0, stream,
                       Whh, ix, hslot, out);
}

// Round 8
// 6328.738 us; speedup vs baseline: 23.9134x; 1.6288x over previous
//
#include <hip/hip_runtime.h>

typedef unsigned int u32_t;

#define S_LEN 2048
#define EDIM  1024
#define HDIM  1024
#define GDIM  4096   // 4*H

#define POISON 0xAAAAAAAAu

#define HSLOT_WORDS ((size_t)S_LEN * HDIM)          // 2M words = 8 MB
#define WS_NEED_8REP (33554432ull + 8ull * 8388608ull)  // ix + 8 replicas

// ---------------------------------------------------------------------------
// Phase A: ix[t][r] = emb[tokens[t]] . W_ih[r] + b_ih[r] + b_hh[r]
// fp32 LDS-tiled GEMM, 64x64 tile, BK=16, 256 threads, 4x4 micro-tile. ~92us.
// (unchanged from the 5612us baseline)
// ---------------------------------------------------------------------------
__global__ __launch_bounds__(256)
void ix_gemm(const int* __restrict__ tokens, const float* __restrict__ emb,
             const float* __restrict__ Wih, const float* __restrict__ bih,
             const float* __restrict__ bhh, float* __restrict__ ix)
{
    __shared__ float As[16][68];
    __shared__ float Bs[16][68];
    const int t0  = blockIdx.x * 64;
    const int r0  = blockIdx.y * 64;
    const int tid = threadIdx.x;
    const int tx  = tid & 15;          // n-direction
    const int ty  = tid >> 4;          // m-direction
    const int m_a = tid & 63;          // staging row
    const int k_a = (tid >> 6) << 2;   // staging k offset: 0,4,8,12

    const float* arow = emb + (size_t)tokens[t0 + m_a] * EDIM + k_a;
    const float* brow = Wih + (size_t)(r0 + m_a) * EDIM + k_a;

    float acc[4][4] = {};
    for (int kk = 0; kk < EDIM; kk += 16) {
        float4 av = *(const float4*)(arow + kk);
        float4 bv = *(const float4*)(brow + kk);
        __syncthreads();
        As[k_a + 0][m_a] = av.x; As[k_a + 1][m_a] = av.y;
        As[k_a + 2][m_a] = av.z; As[k_a + 3][m_a] = av.w;
        Bs[k_a + 0][m_a] = bv.x; Bs[k_a + 1][m_a] = bv.y;
        Bs[k_a + 2][m_a] = bv.z; Bs[k_a + 3][m_a] = bv.w;
        __syncthreads();
#pragma unroll
        for (int k = 0; k < 16; ++k) {
            float4 a = *(const float4*)&As[k][ty << 2];
            float4 b = *(const float4*)&Bs[k][tx << 2];
            acc[0][0] += a.x * b.x; acc[0][1] += a.x * b.y;
            acc[0][2] += a.x * b.z; acc[0][3] += a.x * b.w;
            acc[1][0] += a.y * b.x; acc[1][1] += a.y * b.y;
            acc[1][2] += a.y * b.z; acc[1][3] += a.y * b.w;
            acc[2][0] += a.z * b.x; acc[2][1] += a.z * b.y;
            acc[2][2] += a.z * b.z; acc[2][3] += a.z * b.w;
            acc[3][0] += a.w * b.x; acc[3][1] += a.w * b.y;
            acc[3][2] += a.w * b.z; acc[3][3] += a.w * b.w;
        }
    }
    const int n0 = r0 + (tx << 2);
    float b0 = bih[n0 + 0] + bhh[n0 + 0];
    float b1 = bih[n0 + 1] + bhh[n0 + 1];
    float b2 = bih[n0 + 2] + bhh[n0 + 2];
    float b3 = bih[n0 + 3] + bhh[n0 + 3];
#pragma unroll
    for (int i = 0; i < 4; ++i) {
        int m = t0 + (ty << 2) + i;
        float4 v = make_float4(acc[i][0] + b0, acc[i][1] + b1,
                               acc[i][2] + b2, acc[i][3] + b3);
        *(float4*)(ix + (size_t)m * GDIM + n0) = v;
    }
}

// ---------------------------------------------------------------------------
// Phase B: persistent recurrence — byte-identical protocol to the proven
// 5612us baseline (4x4B sticky relaxed-agent atomic polls + s_sleep(1),
// ix loads at top, hs double-buffer, one barrier/step, async bottom
// prefetch, 256 blocks x 256 threads).
//
// ONE change (templated): producers store h[t][j] to NREP replicas of the
// h-slot array (8 MB stride, all poison-init'd by the harness); each
// consumer block polls ONLY its own XCD's replica (HW_REG_XCC_ID, proven
// in R4). This cuts requesters-per-polled-line 256 -> 32 blocks with ZERO
// change to the poll protocol -- the clean congestion probe that R4 (scope
// bug) and R6 (fan-out actually unchanged; 8-wave compute serialization)
// both failed to run. Producer cost: 8 fire-and-forget agent stores
// instead of 1. Falls back to NREP=1 (= literal baseline) if ws is small.
// ---------------------------------------------------------------------------
__device__ __forceinline__ float fast_sigmoid(float x) {
    return 1.0f / (1.0f + __expf(-x));
}
__device__ __forceinline__ float fast_tanh(float x) {
    return 1.0f - 2.0f / (__expf(2.0f * x) + 1.0f);
}

#define ALOAD(p) __hip_atomic_load((p), __ATOMIC_RELAXED, __HIP_MEMORY_SCOPE_AGENT)
#define ASTORE(p, v) __hip_atomic_store((p), (v), __ATOMIC_RELAXED, __HIP_MEMORY_SCOPE_AGENT)

template <int NREP>
__global__ __launch_bounds__(256)
void lstm_rec(const float* __restrict__ Whh,   // [4H, H]
              const float* __restrict__ ix,    // [S, 4H]
              u32_t* hrep,                     // [NREP][S][H] poison-init
              float* __restrict__ out)         // [H]
{
    const int tid  = threadIdx.x;
    const int wid  = tid >> 6;                 // 0..3
    const int lane = tid & 63;
    const int b    = blockIdx.x;
    const int j    = b * 4 + wid;              // 0..1023

    __shared__ float wlds[4][4][HDIM];         // 64 KB: [wave][gate][k]
    __shared__ float hs[2][HDIM];              // 8 KB, double-buffered
    __shared__ int sh_rep;

    if (tid == 0) {
        if constexpr (NREP > 1) {
            u32_t x;
            asm("s_getreg_b32 %0, hwreg(HW_REG_XCC_ID)" : "=s"(x));
            sh_rep = (int)(x & (NREP - 1));
        } else {
            sh_rep = 0;
        }
    }

    // Stage weights once: 16 rows x 4KB, float4-coalesced.
#pragma unroll
    for (int w = 0; w < 4; ++w)
#pragma unroll
        for (int g = 0; g < 4; ++g) {
            const float* row = Whh + (size_t)(g * HDIM + b * 4 + w) * HDIM;
            *(float4*)&wlds[w][g][tid << 2] = *(const float4*)(row + (tid << 2));
        }
    __syncthreads();                           // also publishes sh_rep

    const u32_t* myslot = hrep + (size_t)sh_rep * HSLOT_WORDS;  // poll target

    float c = 0.0f;
    u32_t p0 = POISON, p1 = POISON, p2 = POISON, p3 = POISON;

    for (int t = 0; t < S_LEN; ++t) {
        // ix contributions (wave-uniform); issued early, consumed post-reduce.
        const float* ixt = ix + (size_t)t * GDIM;
        float bi = ixt[j];
        float bf = ixt[HDIM + j];
        float bg = ixt[2 * HDIM + j];
        float bo = ixt[3 * HDIM + j];

        const int buf = t & 1;
        if (t == 0) {
            *(float4*)&hs[0][tid << 2] = make_float4(0.f, 0.f, 0.f, 0.f);
        } else {
            const u32_t* src = myslot + (size_t)(t - 1) * HDIM + (tid << 2);
            for (;;) {
                bool m0 = (p0 == POISON), m1 = (p1 == POISON);
                bool m2 = (p2 == POISON), m3 = (p3 == POISON);
                if (!(m0 | m1 | m2 | m3)) break;
                if (m0) p0 = ALOAD(src + 0);
                if (m1) p1 = ALOAD(src + 1);
                if (m2) p2 = ALOAD(src + 2);
                if (m3) p3 = ALOAD(src + 3);
                __builtin_amdgcn_s_sleep(1);   // throttle fabric poll storm
            }
            *(float4*)&hs[buf][tid << 2] =
                make_float4(__uint_as_float(p0), __uint_as_float(p1),
                            __uint_as_float(p2), __uint_as_float(p3));
        }
        __syncthreads();   // single barrier/step (hs double-buffered)

        // 4 gates x 16 k-elements per lane; weights + h via ds_read_b128.
        float4 h0 = *(const float4*)&hs[buf][0 * 256 + (lane << 2)];
        float4 h1 = *(const float4*)&hs[buf][1 * 256 + (lane << 2)];
        float4 h2 = *(const float4*)&hs[buf][2 * 256 + (lane << 2)];
        float4 h3 = *(const float4*)&hs[buf][3 * 256 + (lane << 2)];

        float s[4];
#pragma unroll
        for (int g = 0; g < 4; ++g) {
            float4 w0 = *(const float4*)&wlds[wid][g][0 * 256 + (lane << 2)];
            float4 w1 = *(const float4*)&wlds[wid][g][1 * 256 + (lane << 2)];
            float4 w2 = *(const float4*)&wlds[wid][g][2 * 256 + (lane << 2)];
            float4 w3 = *(const float4*)&wlds[wid][g][3 * 256 + (lane << 2)];
            s[g] = w0.x*h0.x + w0.y*h0.y + w0.z*h0.z + w0.w*h0.w
                 + w1.x*h1.x + w1.y*h1.y + w1.z*h1.z + w1.w*h1.w
                 + w2.x*h2.x + w2.y*h2.y + w2.z*h2.z + w2.w*h2.w
                 + w3.x*h3.x + w3.y*h3.y + w3.z*h3.z + w3.w*h3.w;
        }

        // 64-lane butterfly all-reduce, 4 interleaved chains.
#pragma unroll
        for (int sh = 32; sh > 0; sh >>= 1) {
            s[0] += __shfl_xor(s[0], sh, 64);
            s[1] += __shfl_xor(s[1], sh, 64);
            s[2] += __shfl_xor(s[2], sh, 64);
            s[3] += __shfl_xor(s[3], sh, 64);
        }

        float si = s[0] + bi, sf = s[1] + bf, sg = s[2] + bg, so = s[3] + bo;
        float ig = fast_sigmoid(si);
        float fg = fast_sigmoid(sf);
        float og = fast_sigmoid(so);
        float gt = fast_tanh(sg);
        c = fg * c + ig * gt;                  // redundant across lanes (consistent)
        float h = og * fast_tanh(c);

        if (lane == 0) {
            u32_t hb = __float_as_uint(h);
            if (hb == POISON) hb = 0u;         // hang-proof canonicalization
#pragma unroll
            for (int r = 0; r < NREP; ++r)
                ASTORE(hrep + (size_t)r * HSLOT_WORDS + (size_t)t * HDIM + j, hb);
            if (t == S_LEN - 1) out[j] = h;
        }

        // Speculative async prefetch of next step's 4 dwords (own replica);
        // stragglers re-polled at the top of the next iteration.
        const u32_t* nsrc = myslot + (size_t)t * HDIM + (tid << 2);
        p0 = ALOAD(nsrc + 0);
        p1 = ALOAD(nsrc + 1);
        p2 = ALOAD(nsrc + 2);
        p3 = ALOAD(nsrc + 3);
        // No trailing barrier: hs double-buffered; a wave is at most one
        // barrier ahead and writes only the other buffer.
    }
}

// ---------------------------------------------------------------------------
extern "C" void kernel_launch(void* const* d_in, const int* in_sizes, int n_in,
                              void* d_out, int out_size, void* d_ws, size_t ws_size,
                              hipStream_t stream) {
    const int*   tokens = (const int*)  d_in[0];
    const float* emb    = (const float*)d_in[1];
    const float* Wih    = (const float*)d_in[2];
    const float* Whh    = (const float*)d_in[3];
    const float* bih    = (const float*)d_in[4];
    const float* bhh    = (const float*)d_in[5];
    float* out = (float*)d_out;

    float* ix    = (float*)d_ws;                                     // 33.55 MB
    u32_t* hrep  = (u32_t*)((char*)d_ws + (size_t)S_LEN * GDIM * 4); // 8..64 MB

    dim3 gA(S_LEN / 64, GDIM / 64);
    hipLaunchKernelGGL(ix_gemm, gA, dim3(256), 0, stream,
                       tokens, emb, Wih, bih, bhh, ix);
    if (ws_size >= WS_NEED_8REP) {
        hipLaunchKernelGGL(lstm_rec<8>, dim3(256), dim3(256), 0, stream,
                           Whh, ix, hrep, out);
    } else {
        hipLaunchKernelGGL(lstm_rec<1>, dim3(256), dim3(256), 0, stream,
                           Whh, ix, hrep, out);
    }
}